// Round 16
// baseline (74.637 us; speedup 1.0000x reference)
//
#include <hip/hip_runtime.h>

#define WW 1280
#define HH 720
#define NB 8
#define NPIX (HH * WW)            // 921600
#define TOTAL (NB * NPIX)         // 7372800

#define FMAX 4.0f                 // |flow| < 4 -> inlier
#define RHALO 4
#define TH 16                     // 720 = 45*16
#define TW 64                     // 1280 = 20*64
#define TPIX (TH * TW)            // 1024 -> 12.3KB LDS
#define TILES_X (WW / TW)         // 20
#define TILES_Y (HH / TH)         // 45
#define TPB (TILES_X * TILES_Y)   // 900
#define NT (NB * TPB)             // 7200
#define WH (TH + 2 * RHALO)       // 24
#define WWIN (TW + 2 * RHALO)     // 72
#define WPOS (WH * WWIN)          // 1728
#define PAIRS (WH * (WWIN / 2))   // 864 float2 pairs
#define TB 512                    // bigger blocks: 4 blocks/CU = 32 waves = 100%
#define NE 4                      // replay entries/thread (2 pair-iters x 2 | 4 scalar)
#define CAPB 4096

typedef unsigned long long u64;

// Packed accumulator: [sumx:28 | sumy:28 | cnt:8], q = round((2048 - f)*256).
__device__ __forceinline__ u64 enc_add(float fx, float fy) {
    unsigned qx = (unsigned)__float2int_rn((2048.0f - fx) * 256.0f);
    unsigned qy = (unsigned)__float2int_rn((2048.0f - fy) * 256.0f);
    return ((u64)qx << 36) | ((u64)qy << 8) | 1ULL;
}

// ---------------------------------------------------------------------------
// K1: per-batch outlier lists (valid target but |fx|>=4 or |fy|>=4).
// ---------------------------------------------------------------------------
__global__ void k1_outliers(const float* __restrict__ flow,
                            const float* __restrict__ depth,
                            int* __restrict__ nOut, int4* __restrict__ lists) {
    int i = blockIdx.x * blockDim.x + threadIdx.x;
    int p4 = i * 4;
    int b = p4 / NPIX;
    int p = p4 - b * NPIX;
    int y = p / WW;
    int x0 = p - y * WW;
    const float* fb = flow + (size_t)b * 2 * NPIX;
    float4 fx4 = *(const float4*)&fb[p];
    float4 fy4 = *(const float4*)&fb[p + NPIX];
    float fxs[4] = {fx4.x, fx4.y, fx4.z, fx4.w};
    float fys[4] = {fy4.x, fy4.y, fy4.z, fy4.w};
#pragma unroll
    for (int j = 0; j < 4; ++j) {
        float fx = fxs[j], fy = fys[j];
        if (fabsf(fx) < FMAX && fabsf(fy) < FMAX) continue;
        float x2 = (float)(x0 + j) + fx, y2 = (float)y + fy;
        if (!(x2 >= 0.f && y2 >= 0.f && x2 <= (float)(WW - 1) && y2 <= (float)(HH - 1)))
            continue;
        float d = depth[(size_t)b * NPIX + p + j];
        int pos = atomicAdd(&nOut[b], 1);
        if (pos < CAPB)
            lists[b * CAPB + pos] =
                make_int4(p + j, __float_as_int(fx), __float_as_int(fy), __float_as_int(d));
    }
}

// ---------------------------------------------------------------------------
// K2: fused gather, 16x64 tile, 512-thread blocks (4 blocks/CU -> 32 waves/CU).
// Phase A: scan (interior fast path: float2 loads, no guards), capture
// {fx,fy,db,pk+candidate mask}, batched gate reads + conditional atomicMin.
// Phase B: replay, mask-gated reads + ONE packed u64 add per live corner.
// Epilogue: exact int32 unpack + f32 divide.
// pk: b31 valid | b23..20 cand mask | b13..9 lyT+8 | b8..2 lxL+8 | b1 cR | b0 cB
// ---------------------------------------------------------------------------
__global__ void __launch_bounds__(TB, 2)
k2_gather(const float* __restrict__ flow, const float* __restrict__ depth,
          const int* __restrict__ nOut, const int4* __restrict__ lists,
          float* __restrict__ out) {
    __shared__ int mind_t[TPIX];     // 4 KB
    __shared__ u64 acc_t[TPIX];      // 8 KB

    int bid = blockIdx.x;
    { const int c = NT >> 3; bid = (bid & 7) * c + (bid >> 3); }  // XCD swizzle
    const int b   = bid / TPB;
    const int tt  = bid - b * TPB;
    const int tty = tt / TILES_X;
    const int ty0 = tty * TH;
    const int tx0 = (tt - tty * TILES_X) * TW;
    const int tid = threadIdx.x;
    const float* flowb  = flow  + (size_t)b * 2 * NPIX;
    const float* depthb = depth + (size_t)b * NPIX;

    {   // init (TPIX == TB*2)
        int k2 = tid * 2;
        const int IB = __float_as_int(1e30f);
        *(int2*)&mind_t[k2] = make_int2(IB, IB);
        acc_t[k2 + 0] = 0ULL;
        acc_t[k2 + 1] = 0ULL;
    }
    __syncthreads();

    float    fxA[NE], fyA[NE];
    int      dbA[NE];
    unsigned pkA[NE];
#pragma unroll
    for (int q = 0; q < NE; ++q) pkA[q] = 0u;

    const bool interior = (tx0 >= 2 * RHALO) && (tx0 <= WW - TW - 2 * RHALO) &&
                          (ty0 >= 2 * RHALO) && (ty0 <= HH - TH - 2 * RHALO);

// capture + batched gate reads + cond atomicMin + candidate mask (interior)
#define PROC_INT(Q, GXJ, FX, FY, DV)                                          \
    {                                                                          \
        float fx = (FX), fy = (FY);                                            \
        fxA[Q] = fx; fyA[Q] = fy;                                              \
        int db = __float_as_int(DV);                                           \
        dbA[Q] = db;                                                           \
        if (fabsf(fx) < FMAX && fabsf(fy) < FMAX) {                            \
            int xL = (int)floorf((float)(GXJ) + fx);                           \
            int yT = (int)floorf((float)gy + fy);                              \
            int lxL = xL - tx0, lyT = yT - ty0;                                \
            bool m0 = (unsigned)lyT < TH && (unsigned)lxL < TW;                \
            bool m1 = (unsigned)lyT < TH && (unsigned)(lxL + 1) < TW;          \
            bool m2 = (unsigned)(lyT + 1) < TH && (unsigned)lxL < TW;          \
            bool m3 = (unsigned)(lyT + 1) < TH && (unsigned)(lxL + 1) < TW;    \
            int j0 = m0 ? lyT * TW + lxL : 0;                                  \
            int j1 = m1 ? lyT * TW + lxL + 1 : 0;                              \
            int j2 = m2 ? (lyT + 1) * TW + lxL : 0;                            \
            int j3 = m3 ? (lyT + 1) * TW + lxL + 1 : 0;                        \
            int c0 = mind_t[j0];                                               \
            int c1 = mind_t[j1];                                               \
            int c2 = mind_t[j2];                                               \
            int c3 = mind_t[j3];                                               \
            unsigned cm = (unsigned)(m0 && db <= c0) |                         \
                          ((unsigned)(m1 && db <= c1) << 1) |                  \
                          ((unsigned)(m2 && db <= c2) << 2) |                  \
                          ((unsigned)(m3 && db <= c3) << 3);                   \
            pkA[Q] = 0x80000000u | (cm << 20) |                                \
                     (unsigned)((lyT + 8) << 9) | (unsigned)((lxL + 8) << 2);  \
            if (m0 && db < c0) atomicMin(&mind_t[j0], db);                     \
            if (m1 && db < c1) atomicMin(&mind_t[j1], db);                     \
            if (m2 && db < c2) atomicMin(&mind_t[j2], db);                     \
            if (m3 && db < c3) atomicMin(&mind_t[j3], db);                     \
        }                                                                      \
    }

    if (interior) {
#pragma unroll
        for (int it = 0; it < 2; ++it) {
            int g = tid + it * TB;
            if (g >= PAIRS) continue;
            int wy  = g / (WWIN / 2);
            int wx2 = (g - wy * (WWIN / 2)) * 2;
            int gy  = ty0 - RHALO + wy;
            int gx  = tx0 - RHALO + wx2;
            int p   = gy * WW + gx;
            float2 fx2 = *(const float2*)&flowb[p];
            float2 fy2 = *(const float2*)&flowb[p + NPIX];
            float2 d2  = *(const float2*)&depthb[p];
            PROC_INT(it * 2 + 0, gx, fx2.x, fy2.x, d2.x);
            PROC_INT(it * 2 + 1, gx + 1, fx2.y, fy2.y, d2.y);
        }
    } else {
#pragma unroll
        for (int it = 0; it < 4; ++it) {
            int s  = tid + it * TB;
            int wy = s / WWIN;
            int wx = s - wy * WWIN;
            int gy = ty0 - RHALO + wy;
            int gx = tx0 - RHALO + wx;
            if (s >= WPOS || (unsigned)gy >= HH || (unsigned)gx >= WW) continue;
            int p = gy * WW + gx;
            float fx = flowb[p];
            float fy = flowb[p + NPIX];
            float d  = depthb[p];
            fxA[it] = fx; fyA[it] = fy;
            int db = __float_as_int(d);
            dbA[it] = db;
            if (!(fabsf(fx) < FMAX && fabsf(fy) < FMAX)) continue;
            float x2 = (float)gx + fx, y2 = (float)gy + fy;
            if (!(x2 >= 0.f && y2 >= 0.f && x2 <= (float)(WW - 1) && y2 <= (float)(HH - 1)))
                continue;
            int xL = (int)floorf(x2), yT = (int)floorf(y2);
            int xR = min(xL + 1, WW - 1), yB = min(yT + 1, HH - 1);
            int cR = (xR == xL), cB = (yB == yT);
            int lxL = xL - tx0, lyT = yT - ty0;
            int lxR = lxL + (cR ^ 1), lyB = lyT + (cB ^ 1);
            bool m0 = (unsigned)lyT < TH && (unsigned)lxL < TW;
            bool m1 = (unsigned)lyT < TH && (unsigned)lxR < TW;
            bool m2 = (unsigned)lyB < TH && (unsigned)lxL < TW;
            bool m3 = (unsigned)lyB < TH && (unsigned)lxR < TW;
            int j0 = m0 ? lyT * TW + lxL : 0;
            int j1 = m1 ? lyT * TW + lxR : 0;
            int j2 = m2 ? lyB * TW + lxL : 0;
            int j3 = m3 ? lyB * TW + lxR : 0;
            int c0 = mind_t[j0];
            int c1 = mind_t[j1];
            int c2 = mind_t[j2];
            int c3 = mind_t[j3];
            unsigned cm = (unsigned)(m0 && db <= c0) |
                          ((unsigned)(m1 && db <= c1) << 1) |
                          ((unsigned)(m2 && db <= c2) << 2) |
                          ((unsigned)(m3 && db <= c3) << 3);
            pkA[it] = 0x80000000u | (cm << 20) |
                      (unsigned)((lyT + 8) << 9) | (unsigned)((lxL + 8) << 2) |
                      (unsigned)(cR << 1) | (unsigned)cB;
            if (m0 && db < c0) atomicMin(&mind_t[j0], db);
            if (m1 && db < c1) atomicMin(&mind_t[j1], db);
            if (m2 && db < c2) atomicMin(&mind_t[j2], db);
            if (m3 && db < c3) atomicMin(&mind_t[j3], db);
        }
    }
    // ---- outlier mins (only lower mind further; candidate mask stays valid) --
    const int nb = min(nOut[b], CAPB);
    for (int j = tid; j < nb; j += TB) {
        int4 e = lists[b * CAPB + j];
        float fx = __int_as_float(e.y), fy = __int_as_float(e.z);
        int y = e.x / WW, x = e.x - y * WW;
        float x2 = (float)x + fx, y2 = (float)y + fy;
        int xL = min(max((int)floorf(x2), 0), WW - 1);
        int yT = min(max((int)floorf(y2), 0), HH - 1);
        int xR = min(xL + 1, WW - 1), yB = min(yT + 1, HH - 1);
        int lxL = xL - tx0, lxR = xR - tx0, lyT = yT - ty0, lyB = yB - ty0;
        if ((unsigned)lyT < TH) {
            if ((unsigned)lxL < TW) atomicMin(&mind_t[lyT * TW + lxL], e.w);
            if ((unsigned)lxR < TW) atomicMin(&mind_t[lyT * TW + lxR], e.w);
        }
        if ((unsigned)lyB < TH) {
            if ((unsigned)lxL < TW) atomicMin(&mind_t[lyB * TW + lxL], e.w);
            if ((unsigned)lxR < TW) atomicMin(&mind_t[lyB * TW + lxR], e.w);
        }
    }
    __syncthreads();

    // ---- phase B: replay; skip dead entries; mask-gated reads + u64 adds ----
#pragma unroll
    for (int q = 0; q < NE; ++q) {
        unsigned pk = pkA[q];
        unsigned cm = (pk >> 20) & 0xFu;
        if (!cm) continue;                        // no corner can win
        int lxL = (int)((pk >> 2) & 0x7Fu) - 8;
        int lyT = (int)((pk >> 9) & 0x1Fu) - 8;
        int lxR = lxL + 1 - (int)((pk >> 1) & 1u);
        int lyB = lyT + 1 - (int)(pk & 1u);
        bool o0 = (cm & 1u) != 0u;
        bool o1 = (cm & 2u) != 0u;
        bool o2 = (cm & 4u) != 0u;
        bool o3 = (cm & 8u) != 0u;
        int i0 = o0 ? lyT * TW + lxL : 0;
        int i1 = o1 ? lyT * TW + lxR : 0;
        int i2 = o2 ? lyB * TW + lxL : 0;
        int i3 = o3 ? lyB * TW + lxR : 0;
        int v0 = mind_t[i0];          // 4 independent reads -> one wait
        int v1 = mind_t[i1];
        int v2 = mind_t[i2];
        int v3 = mind_t[i3];
        float fx = fxA[q], fy = fyA[q];
        int db = dbA[q];
        u64 enc = enc_add(fx, fy);
        if (o0 && v0 == db) atomicAdd(&acc_t[i0], enc);
        if (o1 && v1 == db) atomicAdd(&acc_t[i1], enc);
        if (o2 && v2 == db) atomicAdd(&acc_t[i2], enc);
        if (o3 && v3 == db) atomicAdd(&acc_t[i3], enc);
    }
    // ---- outlier adds ----
    for (int j = tid; j < nb; j += TB) {
        int4 e = lists[b * CAPB + j];
        float fx = __int_as_float(e.y), fy = __int_as_float(e.z);
        int y = e.x / WW, x = e.x - y * WW;
        float x2 = (float)x + fx, y2 = (float)y + fy;
        int xL = min(max((int)floorf(x2), 0), WW - 1);
        int yT = min(max((int)floorf(y2), 0), HH - 1);
        int xR = min(xL + 1, WW - 1), yB = min(yT + 1, HH - 1);
        int lxL = xL - tx0, lxR = xR - tx0, lyT = yT - ty0, lyB = yB - ty0;
        u64 enc = enc_add(fx, fy);
        int ls[4] = {
            ((unsigned)lyT < TH && (unsigned)lxL < TW) ? lyT * TW + lxL : -1,
            ((unsigned)lyT < TH && (unsigned)lxR < TW) ? lyT * TW + lxR : -1,
            ((unsigned)lyB < TH && (unsigned)lxL < TW) ? lyB * TW + lxL : -1,
            ((unsigned)lyB < TH && (unsigned)lxR < TW) ? lyB * TW + lxR : -1 };
#pragma unroll
        for (int c = 0; c < 4; ++c) {
            int l = ls[c];
            if (l >= 0 && mind_t[l] == e.w) atomicAdd(&acc_t[l], enc);
        }
    }
    __syncthreads();

    // ---- epilogue: EXACT int32 unpack (r = sum - cnt*2^19), f32 divide ----
    {
        int k2 = tid * 2;
        int ly = k2 >> 6;              // /TW
        int lx = k2 & 63;
        float ox[2], oy[2];
#pragma unroll
        for (int j = 0; j < 2; ++j) {
            u64 v = acc_t[k2 + j];
            int cnt  = (int)(v & 0xFFULL);
            int ysum = (int)((v >> 8) & 0xFFFFFFFULL);
            int xsum = (int)(v >> 36);
            if (cnt) {
                int rx = xsum - (cnt << 19);       // exact (fields < 2^28)
                int ry = ysum - (cnt << 19);
                float inv = 1.0f / ((float)cnt * 256.0f);
                ox[j] = (float)rx * inv;
                oy[j] = (float)ry * inv;
            } else {
                ox[j] = 0.f; oy[j] = 0.f;
            }
        }
        size_t o = (size_t)b * 2 * NPIX + (size_t)(ty0 + ly) * WW + (tx0 + lx);
        *(float2*)&out[o]        = make_float2(ox[0], ox[1]);
        *(float2*)&out[o + NPIX] = make_float2(oy[0], oy[1]);
    }
}

extern "C" void kernel_launch(void* const* d_in, const int* in_sizes, int n_in,
                              void* d_out, int out_size, void* d_ws, size_t ws_size,
                              hipStream_t stream) {
    const float* flow  = (const float*)d_in[0];
    const float* depth = (const float*)d_in[1];
    float* out = (float*)d_out;

    int*  nOut  = (int*)d_ws;                 // 16 ints (first NB used)
    int4* lists = (int4*)((char*)d_ws + 64);  // NB * CAPB entries

    hipMemsetAsync(nOut, 0, 64, stream);
    k1_outliers<<<TOTAL / 4 / 256, 256, 0, stream>>>(flow, depth, nOut, lists);
    k2_gather  <<<NT, TB, 0, stream>>>(flow, depth, nOut, lists, out);
}

// Round 17
// 69.738 us; speedup vs baseline: 1.0702x; 1.0702x over previous
//
#include <hip/hip_runtime.h>

#define WW 1280
#define HH 720
#define NB 8
#define NPIX (HH * WW)            // 921600
#define TOTAL (NB * NPIX)         // 7372800

#define FMAX 4.0f                 // |flow| < 4 -> inlier
#define RHALO 4
#define TH 24                     // 720 = 30*24
#define TW 64                     // 1280 = 20*64
#define TPIX (TH * TW)            // 1536 -> 18.4KB LDS
#define TILES_X (WW / TW)         // 20
#define TILES_Y (HH / TH)         // 30
#define TPB (TILES_X * TILES_Y)   // 600
#define NT (NB * TPB)             // 4800 (divisible by 8)
#define WH (TH + 2 * RHALO)       // 32
#define WWIN (TW + 2 * RHALO)     // 72
#define WPOS (WH * WWIN)          // 2304 (overlap 1.50x vs 1.69x at TH=16)
#define PAIRS (WH * (WWIN / 2))   // 1152 float2 pairs
#define TB 512
#define NE 6                      // replay entries (3 pair-iters x 2 | 5 scalar)
#define CAPB 4096

typedef unsigned long long u64;

// Packed accumulator: [sumx:28 | sumy:28 | cnt:8], q = round((2048 - f)*256).
// <=162 writers/target -> fields < 2^28, cnt < 256: no cross-field carries.
__device__ __forceinline__ u64 enc_add(float fx, float fy) {
    unsigned qx = (unsigned)__float2int_rn((2048.0f - fx) * 256.0f);
    unsigned qy = (unsigned)__float2int_rn((2048.0f - fy) * 256.0f);
    return ((u64)qx << 36) | ((u64)qy << 8) | 1ULL;
}

// ---------------------------------------------------------------------------
// K1: per-batch outlier lists (valid target but |fx|>=4 or |fy|>=4).
// ---------------------------------------------------------------------------
__global__ void k1_outliers(const float* __restrict__ flow,
                            const float* __restrict__ depth,
                            int* __restrict__ nOut, int4* __restrict__ lists) {
    int i = blockIdx.x * blockDim.x + threadIdx.x;
    int p4 = i * 4;
    int b = p4 / NPIX;
    int p = p4 - b * NPIX;
    int y = p / WW;
    int x0 = p - y * WW;
    const float* fb = flow + (size_t)b * 2 * NPIX;
    float4 fx4 = *(const float4*)&fb[p];
    float4 fy4 = *(const float4*)&fb[p + NPIX];
    float fxs[4] = {fx4.x, fx4.y, fx4.z, fx4.w};
    float fys[4] = {fy4.x, fy4.y, fy4.z, fy4.w};
#pragma unroll
    for (int j = 0; j < 4; ++j) {
        float fx = fxs[j], fy = fys[j];
        if (fabsf(fx) < FMAX && fabsf(fy) < FMAX) continue;
        float x2 = (float)(x0 + j) + fx, y2 = (float)y + fy;
        if (!(x2 >= 0.f && y2 >= 0.f && x2 <= (float)(WW - 1) && y2 <= (float)(HH - 1)))
            continue;
        float d = depth[(size_t)b * NPIX + p + j];
        int pos = atomicAdd(&nOut[b], 1);
        if (pos < CAPB)
            lists[b * CAPB + pos] =
                make_int4(p + j, __float_as_int(fx), __float_as_int(fy), __float_as_int(d));
    }
}

// ---------------------------------------------------------------------------
// K2: fused gather, 24x64 tile (overlap 1.50x), 512-thread blocks.
// Phase A: scan (interior fast path: float2 loads, no guards), capture
// {fx,fy,db,pk+candidate mask}, batched gate reads + conditional atomicMin.
// Phase B: replay, mask-gated reads + ONE packed u64 add per live corner.
// Epilogue: exact int32 unpack + f32 divide.
// pk: b31 valid | b23..20 cand mask | b13..9 lyT+8 | b8..2 lxL+8 | b1 cR | b0 cB
// ---------------------------------------------------------------------------
__global__ void __launch_bounds__(TB, 2)
k2_gather(const float* __restrict__ flow, const float* __restrict__ depth,
          const int* __restrict__ nOut, const int4* __restrict__ lists,
          float* __restrict__ out) {
    __shared__ int mind_t[TPIX];     // 6 KB
    __shared__ u64 acc_t[TPIX];      // 12.3 KB

    int bid = blockIdx.x;
    { const int c = NT >> 3; bid = (bid & 7) * c + (bid >> 3); }  // XCD swizzle
    const int b   = bid / TPB;
    const int tt  = bid - b * TPB;
    const int tty = tt / TILES_X;
    const int ty0 = tty * TH;
    const int tx0 = (tt - tty * TILES_X) * TW;
    const int tid = threadIdx.x;
    const float* flowb  = flow  + (size_t)b * 2 * NPIX;
    const float* depthb = depth + (size_t)b * NPIX;

    {   // init (TPIX == TB*3)
        const int IB = __float_as_int(1e30f);
#pragma unroll
        for (int i = 0; i < 3; ++i) {
            int k = tid + i * TB;
            mind_t[k] = IB;
            acc_t[k]  = 0ULL;
        }
    }
    __syncthreads();

    float    fxA[NE], fyA[NE];
    int      dbA[NE];
    unsigned pkA[NE];
#pragma unroll
    for (int q = 0; q < NE; ++q) pkA[q] = 0u;

    const bool interior = (tx0 >= 2 * RHALO) && (tx0 <= WW - TW - 2 * RHALO) &&
                          (ty0 >= 2 * RHALO) && (ty0 <= HH - TH - 2 * RHALO);

// capture + batched gate reads + cond atomicMin + candidate mask (interior)
#define PROC_INT(Q, GXJ, FX, FY, DV)                                          \
    {                                                                          \
        float fx = (FX), fy = (FY);                                            \
        fxA[Q] = fx; fyA[Q] = fy;                                              \
        int db = __float_as_int(DV);                                           \
        dbA[Q] = db;                                                           \
        if (fabsf(fx) < FMAX && fabsf(fy) < FMAX) {                            \
            int xL = (int)floorf((float)(GXJ) + fx);                           \
            int yT = (int)floorf((float)gy + fy);                              \
            int lxL = xL - tx0, lyT = yT - ty0;                                \
            bool m0 = (unsigned)lyT < TH && (unsigned)lxL < TW;                \
            bool m1 = (unsigned)lyT < TH && (unsigned)(lxL + 1) < TW;          \
            bool m2 = (unsigned)(lyT + 1) < TH && (unsigned)lxL < TW;          \
            bool m3 = (unsigned)(lyT + 1) < TH && (unsigned)(lxL + 1) < TW;    \
            int j0 = m0 ? lyT * TW + lxL : 0;                                  \
            int j1 = m1 ? lyT * TW + lxL + 1 : 0;                              \
            int j2 = m2 ? (lyT + 1) * TW + lxL : 0;                            \
            int j3 = m3 ? (lyT + 1) * TW + lxL + 1 : 0;                        \
            int c0 = mind_t[j0];                                               \
            int c1 = mind_t[j1];                                               \
            int c2 = mind_t[j2];                                               \
            int c3 = mind_t[j3];                                               \
            unsigned cm = (unsigned)(m0 && db <= c0) |                         \
                          ((unsigned)(m1 && db <= c1) << 1) |                  \
                          ((unsigned)(m2 && db <= c2) << 2) |                  \
                          ((unsigned)(m3 && db <= c3) << 3);                   \
            pkA[Q] = 0x80000000u | (cm << 20) |                                \
                     (unsigned)((lyT + 8) << 9) | (unsigned)((lxL + 8) << 2);  \
            if (m0 && db < c0) atomicMin(&mind_t[j0], db);                     \
            if (m1 && db < c1) atomicMin(&mind_t[j1], db);                     \
            if (m2 && db < c2) atomicMin(&mind_t[j2], db);                     \
            if (m3 && db < c3) atomicMin(&mind_t[j3], db);                     \
        }                                                                      \
    }

    if (interior) {
#pragma unroll
        for (int it = 0; it < 3; ++it) {
            int g = tid + it * TB;
            if (g >= PAIRS) continue;
            int wy  = g / (WWIN / 2);
            int wx2 = (g - wy * (WWIN / 2)) * 2;
            int gy  = ty0 - RHALO + wy;
            int gx  = tx0 - RHALO + wx2;
            int p   = gy * WW + gx;
            float2 fx2 = *(const float2*)&flowb[p];
            float2 fy2 = *(const float2*)&flowb[p + NPIX];
            float2 d2  = *(const float2*)&depthb[p];
            PROC_INT(it * 2 + 0, gx, fx2.x, fy2.x, d2.x);
            PROC_INT(it * 2 + 1, gx + 1, fx2.y, fy2.y, d2.y);
        }
    } else {
#pragma unroll
        for (int it = 0; it < 5; ++it) {
            int s  = tid + it * TB;
            int wy = s / WWIN;
            int wx = s - wy * WWIN;
            int gy = ty0 - RHALO + wy;
            int gx = tx0 - RHALO + wx;
            if (s >= WPOS || (unsigned)gy >= HH || (unsigned)gx >= WW) continue;
            int p = gy * WW + gx;
            float fx = flowb[p];
            float fy = flowb[p + NPIX];
            float d  = depthb[p];
            fxA[it] = fx; fyA[it] = fy;
            int db = __float_as_int(d);
            dbA[it] = db;
            if (!(fabsf(fx) < FMAX && fabsf(fy) < FMAX)) continue;
            float x2 = (float)gx + fx, y2 = (float)gy + fy;
            if (!(x2 >= 0.f && y2 >= 0.f && x2 <= (float)(WW - 1) && y2 <= (float)(HH - 1)))
                continue;
            int xL = (int)floorf(x2), yT = (int)floorf(y2);
            int xR = min(xL + 1, WW - 1), yB = min(yT + 1, HH - 1);
            int cR = (xR == xL), cB = (yB == yT);
            int lxL = xL - tx0, lyT = yT - ty0;
            int lxR = lxL + (cR ^ 1), lyB = lyT + (cB ^ 1);
            bool m0 = (unsigned)lyT < TH && (unsigned)lxL < TW;
            bool m1 = (unsigned)lyT < TH && (unsigned)lxR < TW;
            bool m2 = (unsigned)lyB < TH && (unsigned)lxL < TW;
            bool m3 = (unsigned)lyB < TH && (unsigned)lxR < TW;
            int j0 = m0 ? lyT * TW + lxL : 0;
            int j1 = m1 ? lyT * TW + lxR : 0;
            int j2 = m2 ? lyB * TW + lxL : 0;
            int j3 = m3 ? lyB * TW + lxR : 0;
            int c0 = mind_t[j0];
            int c1 = mind_t[j1];
            int c2 = mind_t[j2];
            int c3 = mind_t[j3];
            unsigned cm = (unsigned)(m0 && db <= c0) |
                          ((unsigned)(m1 && db <= c1) << 1) |
                          ((unsigned)(m2 && db <= c2) << 2) |
                          ((unsigned)(m3 && db <= c3) << 3);
            pkA[it] = 0x80000000u | (cm << 20) |
                      (unsigned)((lyT + 8) << 9) | (unsigned)((lxL + 8) << 2) |
                      (unsigned)(cR << 1) | (unsigned)cB;
            if (m0 && db < c0) atomicMin(&mind_t[j0], db);
            if (m1 && db < c1) atomicMin(&mind_t[j1], db);
            if (m2 && db < c2) atomicMin(&mind_t[j2], db);
            if (m3 && db < c3) atomicMin(&mind_t[j3], db);
        }
    }
    // ---- outlier mins (only lower mind further; candidate mask stays valid) --
    const int nb = min(nOut[b], CAPB);
    for (int j = tid; j < nb; j += TB) {
        int4 e = lists[b * CAPB + j];
        float fx = __int_as_float(e.y), fy = __int_as_float(e.z);
        int y = e.x / WW, x = e.x - y * WW;
        float x2 = (float)x + fx, y2 = (float)y + fy;
        int xL = min(max((int)floorf(x2), 0), WW - 1);
        int yT = min(max((int)floorf(y2), 0), HH - 1);
        int xR = min(xL + 1, WW - 1), yB = min(yT + 1, HH - 1);
        int lxL = xL - tx0, lxR = xR - tx0, lyT = yT - ty0, lyB = yB - ty0;
        if ((unsigned)lyT < TH) {
            if ((unsigned)lxL < TW) atomicMin(&mind_t[lyT * TW + lxL], e.w);
            if ((unsigned)lxR < TW) atomicMin(&mind_t[lyT * TW + lxR], e.w);
        }
        if ((unsigned)lyB < TH) {
            if ((unsigned)lxL < TW) atomicMin(&mind_t[lyB * TW + lxL], e.w);
            if ((unsigned)lxR < TW) atomicMin(&mind_t[lyB * TW + lxR], e.w);
        }
    }
    __syncthreads();

    // ---- phase B: replay; skip dead entries; mask-gated reads + u64 adds ----
#pragma unroll
    for (int q = 0; q < NE; ++q) {
        unsigned pk = pkA[q];
        unsigned cm = (pk >> 20) & 0xFu;
        if (!cm) continue;                        // no corner can win
        int lxL = (int)((pk >> 2) & 0x7Fu) - 8;
        int lyT = (int)((pk >> 9) & 0x1Fu) - 8;
        int lxR = lxL + 1 - (int)((pk >> 1) & 1u);
        int lyB = lyT + 1 - (int)(pk & 1u);
        bool o0 = (cm & 1u) != 0u;
        bool o1 = (cm & 2u) != 0u;
        bool o2 = (cm & 4u) != 0u;
        bool o3 = (cm & 8u) != 0u;
        int i0 = o0 ? lyT * TW + lxL : 0;
        int i1 = o1 ? lyT * TW + lxR : 0;
        int i2 = o2 ? lyB * TW + lxL : 0;
        int i3 = o3 ? lyB * TW + lxR : 0;
        int v0 = mind_t[i0];          // 4 independent reads -> one wait
        int v1 = mind_t[i1];
        int v2 = mind_t[i2];
        int v3 = mind_t[i3];
        float fx = fxA[q], fy = fyA[q];
        int db = dbA[q];
        u64 enc = enc_add(fx, fy);
        if (o0 && v0 == db) atomicAdd(&acc_t[i0], enc);
        if (o1 && v1 == db) atomicAdd(&acc_t[i1], enc);
        if (o2 && v2 == db) atomicAdd(&acc_t[i2], enc);
        if (o3 && v3 == db) atomicAdd(&acc_t[i3], enc);
    }
    // ---- outlier adds ----
    for (int j = tid; j < nb; j += TB) {
        int4 e = lists[b * CAPB + j];
        float fx = __int_as_float(e.y), fy = __int_as_float(e.z);
        int y = e.x / WW, x = e.x - y * WW;
        float x2 = (float)x + fx, y2 = (float)y + fy;
        int xL = min(max((int)floorf(x2), 0), WW - 1);
        int yT = min(max((int)floorf(y2), 0), HH - 1);
        int xR = min(xL + 1, WW - 1), yB = min(yT + 1, HH - 1);
        int lxL = xL - tx0, lxR = xR - tx0, lyT = yT - ty0, lyB = yB - ty0;
        u64 enc = enc_add(fx, fy);
        int ls[4] = {
            ((unsigned)lyT < TH && (unsigned)lxL < TW) ? lyT * TW + lxL : -1,
            ((unsigned)lyT < TH && (unsigned)lxR < TW) ? lyT * TW + lxR : -1,
            ((unsigned)lyB < TH && (unsigned)lxL < TW) ? lyB * TW + lxL : -1,
            ((unsigned)lyB < TH && (unsigned)lxR < TW) ? lyB * TW + lxR : -1 };
#pragma unroll
        for (int c = 0; c < 4; ++c) {
            int l = ls[c];
            if (l >= 0 && mind_t[l] == e.w) atomicAdd(&acc_t[l], enc);
        }
    }
    __syncthreads();

    // ---- epilogue: EXACT int32 unpack (r = sum - cnt*2^19), f32 divide ----
#pragma unroll
    for (int i = 0; i < 3; ++i) {
        int k = tid + i * TB;
        int ly = k >> 6;               // /TW
        int lx = k & 63;
        u64 v = acc_t[k];
        int cnt  = (int)(v & 0xFFULL);
        int ysum = (int)((v >> 8) & 0xFFFFFFFULL);
        int xsum = (int)(v >> 36);
        float oxv = 0.f, oyv = 0.f;
        if (cnt) {
            int rx = xsum - (cnt << 19);           // exact (fields < 2^28)
            int ry = ysum - (cnt << 19);
            float inv = 1.0f / ((float)cnt * 256.0f);
            oxv = (float)rx * inv;
            oyv = (float)ry * inv;
        }
        size_t o = (size_t)b * 2 * NPIX + (size_t)(ty0 + ly) * WW + (tx0 + lx);
        out[o]        = oxv;
        out[o + NPIX] = oyv;
    }
}

extern "C" void kernel_launch(void* const* d_in, const int* in_sizes, int n_in,
                              void* d_out, int out_size, void* d_ws, size_t ws_size,
                              hipStream_t stream) {
    const float* flow  = (const float*)d_in[0];
    const float* depth = (const float*)d_in[1];
    float* out = (float*)d_out;

    int*  nOut  = (int*)d_ws;                 // 16 ints (first NB used)
    int4* lists = (int4*)((char*)d_ws + 64);  // NB * CAPB entries

    hipMemsetAsync(nOut, 0, 64, stream);
    k1_outliers<<<TOTAL / 4 / 256, 256, 0, stream>>>(flow, depth, nOut, lists);
    k2_gather  <<<NT, TB, 0, stream>>>(flow, depth, nOut, lists, out);
}